// Round 10
// baseline (177.092 us; speedup 1.0000x reference)
//
#include <hip/hip_runtime.h>
#include <math.h>

// Problem dims (fixed by setup_inputs)
#define HW   16384
#define BS   16
#define C    256
#define NQ   100
#define NQP  112          // padded nq (7 x 16)
#define Hh   128
#define Ww   128

// output layout offsets (floats)
#define SIM_OFF   3200                 // after proposal_for_loss [16,100,2]
#define PROPS_OFF (3200 + 26214400)    // after similarity [16,100,16384]

#define BM 128           // hw per block (= one y-row of the 128x128 grid)
#define BK 32            // k per step (== MFMA K)
#define NBLK (HW / BM)   // 128 partials per row

typedef _Float16 half8 __attribute__((ext_vector_type(8)));
typedef float f32x4 __attribute__((ext_vector_type(4)));

__device__ __forceinline__ void gll16(const void* gp, void* lp) {
    __builtin_amdgcn_global_load_lds((const __attribute__((address_space(1))) void*)gp,
                                     (__attribute__((address_space(3))) void*)lp, 16, 0, 0);
}

__device__ __forceinline__ void split8(const float4 a, const float4 b, half8& hi, half8& lo) {
    float f[8] = {a.x, a.y, a.z, a.w, b.x, b.y, b.z, b.w};
    _Float16 h[8], l[8];
    #pragma unroll
    for (int i = 0; i < 8; ++i) {
        h[i] = (_Float16)f[i];
        l[i] = (_Float16)(f[i] - (float)h[i]);
    }
    hi = *(half8*)h;
    lo = *(half8*)l;
}

// ---------------- S pre-split kernel ----------------
// S [nq, bs, c] fp32 -> Shi/Slo [bs][112][256] fp16 (rows >= NQ zero)
__global__ __launch_bounds__(256) void split_S_kernel(const float* __restrict__ S,
                                                      _Float16* __restrict__ shi,
                                                      _Float16* __restrict__ slo)
{
    int idx4 = blockIdx.x * 256 + threadIdx.x;
    int idx = idx4 * 4;
    if (idx >= BS * NQP * C) return;
    int b = idx / (NQP * C);
    int rem = idx - b * (NQP * C);
    int n = rem / C;
    int k = rem - n * C;
    float4 v = make_float4(0.f, 0.f, 0.f, 0.f);
    if (n < NQ) v = *(const float4*)(S + ((size_t)n * BS + b) * C + k);
    _Float16 h[4], l[4];
    float f[4] = {v.x, v.y, v.z, v.w};
    #pragma unroll
    for (int i = 0; i < 4; ++i) {
        h[i] = (_Float16)f[i];
        l[i] = (_Float16)(f[i] - (float)h[i]);
    }
    *(uint2*)(shi + idx) = *(uint2*)h;
    *(uint2*)(slo + idx) = *(uint2*)l;
}

// ---------------- barrier-free dbuf split-fp16 MFMA GEMM + fused row stats ----------------
// sim[b][n][k] = sum_c S[n][b][c] * Q[k][b][c]
// A = Q (hw rows), B = S (nq cols). Each wave stages ONLY its own Q rows into
// LDS (global_load_lds, swizzled source) -> no cross-wave LDS sharing -> NO
// K-loop barriers. Q double-buffered; stage(next) issued after ds_read(cur) +
// S loads, so the compiler's S-wait is a counted vmcnt leaving prefetch in
// flight. S hi/lo read direct from the L2-resident pre-split workspace.
template<bool USE_WS>
__global__ __launch_bounds__(256, 3) void gemm_kernel(const float* __restrict__ Q,
                                                      const float* __restrict__ S,
                                                      const _Float16* __restrict__ ShiG,
                                                      const _Float16* __restrict__ SloG,
                                                      float* __restrict__ out,
                                                      float* __restrict__ pm,
                                                      float* __restrict__ pz,
                                                      float* __restrict__ pwx,
                                                      int* __restrict__ pidx)
{
    __shared__ __align__(16) float Qf[2][BM * BK];   // 2 x 16 KB, swizzled chunks
    __shared__ __align__(16) float Ws[NQP][4][4];    // per-(nq,wid) {m, idx, z, wx}

    const int b    = blockIdx.y;
    const int hw0  = blockIdx.x * BM;
    const int t    = threadIdx.x;
    const int wid  = t >> 6;
    const int lane = t & 63;
    const int lr   = lane & 15;    // A-row / B-col within fragment
    const int lg   = lane >> 4;    // k-group (0..3)

    // acc[am][bn]: hw = wid*32 + 16*am + 4*lg + j, nq = 16*bn + lr
    f32x4 acc[2][7];
    #pragma unroll
    for (int am = 0; am < 2; ++am)
        #pragma unroll
        for (int bn = 0; bn < 7; ++bn)
            acc[am][bn] = (f32x4)(0.f);

    // staging: wave w covers rows w*32..w*32+31 (4 gll16, 8 rows each).
    // lane l -> row rt+(l>>3), LDS chunk slot (l&7); source chunk pre-swizzled
    // so LDS slot c of row r holds global chunk c ^ (r&7).
    const int q_r8 = lane >> 3;
    const int q_gc = (lane & 7) ^ q_r8;

    auto stageQ = [&](int buf, int k0) {
        #pragma unroll
        for (int p = 0; p < 4; ++p) {
            int rt = wid * 32 + p * 8;
            const float* g = Q + ((size_t)(hw0 + rt + q_r8) * BS + b) * C + k0 + q_gc * 4;
            gll16(g, &Qf[buf][rt * BK]);
        }
    };

    stageQ(0, 0);
    #pragma unroll 2
    for (int step = 0; step < 8; ++step) {
        const int k0  = step * BK;
        const int cur = step & 1;

        // 1. Q fragment ds_reads FIRST (any conservative vmcnt wait here drains
        //    only last step's 4 gll16, aged by a full compute phase)
        float4 qa[2], qb[2];
        #pragma unroll
        for (int am = 0; am < 2; ++am) {
            int row = wid * 32 + 16 * am + lr;
            int r7 = row & 7;
            qa[am] = *(const float4*)&Qf[cur][row * BK + (((2 * lg + 0) ^ r7) << 2)];
            qb[am] = *(const float4*)&Qf[cur][row * BK + (((2 * lg + 1) ^ r7) << 2)];
        }

        // 2. S loads (L2-resident), issued BEFORE stage(next) so the MFMA's
        //    S-wait is counted and leaves the gll16 prefetch in flight
        half8 shi[7], slo[7];
        #pragma unroll
        for (int bn = 0; bn < 7; ++bn) {
            if (USE_WS) {
                size_t off = ((size_t)b * NQP + 16 * bn + lr) * C + k0 + 8 * lg;
                shi[bn] = *(const half8*)(ShiG + off);
                slo[bn] = *(const half8*)(SloG + off);
            } else {
                int row = 16 * bn + lr;
                if (row < NQ) {
                    const float* g = S + ((size_t)row * BS + b) * C + k0 + 8 * lg;
                    float4 sa = *(const float4*)g;
                    float4 sb = *(const float4*)(g + 4);
                    split8(sa, sb, shi[bn], slo[bn]);
                } else {
                    shi[bn] = (half8)(_Float16)0.f;
                    slo[bn] = (half8)(_Float16)0.f;
                }
            }
        }

        // 3. prefetch next K tile (no barrier; wave-private rows)
        if (step < 7) stageQ(cur ^ 1, k0 + BK);

        // 4. split Q (overlaps S latency)
        half8 qhi[2], qlo[2];
        #pragma unroll
        for (int am = 0; am < 2; ++am) split8(qa[am], qb[am], qhi[am], qlo[am]);

        // 5. 3-pass MFMA
        #pragma unroll
        for (int bn = 0; bn < 7; ++bn)
            #pragma unroll
            for (int am = 0; am < 2; ++am) {
                acc[am][bn] = __builtin_amdgcn_mfma_f32_16x16x32_f16(qhi[am], shi[bn], acc[am][bn], 0, 0, 0);
                acc[am][bn] = __builtin_amdgcn_mfma_f32_16x16x32_f16(qhi[am], slo[bn], acc[am][bn], 0, 0, 0);
                acc[am][bn] = __builtin_amdgcn_mfma_f32_16x16x32_f16(qlo[am], shi[bn], acc[am][bn], 0, 0, 0);
            }
    }

    // ---- epilogue: sim store (dwordx4) + per-row stats (lane-local) ----
    float* simb = out + SIM_OFF;
    const int hwl0 = wid * 32 + 4 * lg;            // local hw base (0..127)
    #pragma unroll
    for (int bn = 0; bn < 7; ++bn) {
        int nq = 16 * bn + lr;
        if (nq < NQ) {
            size_t rbase = ((size_t)(b * NQ + nq)) * HW + hw0 + hwl0;
            *(float4*)&simb[rbase]      = make_float4(acc[0][bn][0], acc[0][bn][1], acc[0][bn][2], acc[0][bn][3]);
            *(float4*)&simb[rbase + 16] = make_float4(acc[1][bn][0], acc[1][bn][1], acc[1][bn][2], acc[1][bn][3]);
        }
        if (USE_WS) {
            // per-thread max/argmax over 8 register values (ascending local idx,
            // strict > -> lowest idx wins ties)
            float vm = acc[0][bn][0];
            int   ci = hwl0;
            #pragma unroll
            for (int am = 0; am < 2; ++am)
                #pragma unroll
                for (int j = 0; j < 4; ++j) {
                    float v = acc[am][bn][j];
                    if (v > vm) { vm = v; ci = hwl0 + 16 * am + j; }
                }
            float z = 0.f, wx = 0.f;
            #pragma unroll
            for (int am = 0; am < 2; ++am)
                #pragma unroll
                for (int j = 0; j < 4; ++j) {
                    float e = __expf(acc[am][bn][j] - vm);
                    z += e;
                    wx += e * ((float)(hwl0 + 16 * am + j) + 0.5f);   // x = local hw (BM==128)
                }
            // 2-step ladder over the 4 lg-lanes holding this nq (xor 16, 32)
            #pragma unroll
            for (int off = 16; off < 64; off <<= 1) {
                float om = __shfl_xor(vm, off);
                int   oc = __shfl_xor(ci, off);
                float oz = __shfl_xor(z, off);
                float ox = __shfl_xor(wx, off);
                bool take = (om > vm) || (om == vm && oc < ci);
                float mn = take ? om : vm;
                float ss = __expf(vm - mn);
                float so = __expf(om - mn);
                z  = z * ss + oz * so;
                wx = wx * ss + ox * so;
                vm = mn;
                ci = take ? oc : ci;
            }
            if (lg == 0) {
                f32x4 tu = {vm, __int_as_float(ci), z, wx};
                *(f32x4*)&Ws[nq][wid][0] = tu;
            }
        }
    }
    if (USE_WS) {
        __syncthreads();
        if (t < NQ) {
            int nq = t;
            float M = -3.4e38f; int gi = 0;
            float mw[4], zw[4], xw[4]; int cw[4];
            #pragma unroll
            for (int w = 0; w < 4; ++w) {
                f32x4 tu = *(const f32x4*)&Ws[nq][w][0];
                mw[w] = tu[0]; cw[w] = __float_as_int(tu[1]); zw[w] = tu[2]; xw[w] = tu[3];
                if (mw[w] > M || (mw[w] == M && cw[w] < gi)) { M = mw[w]; gi = cw[w]; }
            }
            float Zp = 0.f, WXp = 0.f;
            #pragma unroll
            for (int w = 0; w < 4; ++w) {
                float s = __expf(mw[w] - M);
                Zp  += zw[w] * s;
                WXp += xw[w] * s;
            }
            // block-contiguous partials: single writer per line; y uniform = blockIdx.x
            size_t pbase = ((size_t)b * NBLK + blockIdx.x) * NQ + nq;
            pm[pbase] = M; pz[pbase] = Zp; pwx[pbase] = WXp;
            pidx[pbase] = hw0 + gi;
        }
    }
}

// ---------------- finalize: combine 128 partials per row (2 per lane) ----------------
__global__ __launch_bounds__(256) void finalize_kernel(const float* __restrict__ sim,
                                                       const float* __restrict__ pm,
                                                       const float* __restrict__ pz,
                                                       const float* __restrict__ pwx,
                                                       const int* __restrict__ pidx,
                                                       float* __restrict__ out)
{
    const int rglob = blockIdx.x * 4 + (threadIdx.x >> 6);  // 0..1599 = b*NQ + n
    const int lane  = threadIdx.x & 63;
    const int b     = rglob / NQ;
    const int n     = rglob - b * NQ;
    const size_t b0 = ((size_t)b * NBLK + lane) * NQ + n;
    const size_t b1 = ((size_t)b * NBLK + lane + 64) * NQ + n;

    float m0 = pm[b0],   m1 = pm[b1];
    float z0 = pz[b0],   z1 = pz[b1];
    float x0 = pwx[b0],  x1 = pwx[b1];
    int   i0 = pidx[b0], i1 = pidx[b1];

    // merge the lane's two partials (i0 < i1 always: block lane < lane+64)
    float v; int vi;
    if (m0 >= m1) { v = m0; vi = i0; } else { v = m1; vi = i1; }
    #pragma unroll
    for (int off = 1; off < 64; off <<= 1) {
        float ov = __shfl_xor(v, off);
        int   oi = __shfl_xor(vi, off);
        if (ov > v || (ov == v && oi < vi)) { v = ov; vi = oi; }
    }
    float s0 = __expf(m0 - v), s1 = __expf(m1 - v);
    float Z  = z0 * s0 + z1 * s1;
    float WX = x0 * s0 + x1 * s1;
    // y per partial block == block index (BM=128 -> one grid row per block)
    float WY = z0 * s0 * ((float)lane + 0.5f) + z1 * s1 * ((float)lane + 64.5f);
    #pragma unroll
    for (int off = 1; off < 64; off <<= 1) {
        Z  += __shfl_xor(Z, off);
        WX += __shfl_xor(WX, off);
        WY += __shfl_xor(WY, off);
    }
    if (lane == 0) {
        out[(size_t)rglob * 2 + 0] = (WX / Z) * (1.f / 128.f);
        out[(size_t)rglob * 2 + 1] = (WY / Z) * (1.f / 128.f);
        const float* srow = sim + (size_t)rglob * HW;
        int pr = vi >> 7, pc = vi & 127;
        float ls = 0.f, lx = 0.f, ly = 0.f;
        #pragma unroll
        for (int dr = -1; dr <= 1; ++dr) {
            #pragma unroll
            for (int dc = -1; dc <= 1; ++dc) {
                int r = pr + dr, c = pc + dc;
                if (r >= 0 && r < Ww && c >= 0 && c < Hh) {
                    int k = r * Hh + c;
                    float e = __expf(srow[k] - v);
                    ls += e;
                    lx += e * ((float)(k & 127) + 0.5f);
                    ly += e * ((float)(k >> 7) + 0.5f);
                }
            }
        }
        float denom = ls + 1e-10f * Z;
        out[PROPS_OFF + (size_t)rglob * 2 + 0] = (lx / denom) * (1.f / 128.f);
        out[PROPS_OFF + (size_t)rglob * 2 + 1] = (ly / denom) * (1.f / 128.f);
    }
}

// ---------------- fallback row-reduction kernel (no-ws path) ----------------
__global__ __launch_bounds__(256) void reduce_kernel(const float* __restrict__ sim,
                                                     float* __restrict__ out)
{
    __shared__ float rowbuf[HW];
    __shared__ float s_pm[4];
    __shared__ int   s_pi[4];
    __shared__ float s_red[4][3];
    __shared__ float s_gmax;
    __shared__ int   s_gidx;

    const int row = blockIdx.x;
    const int t   = threadIdx.x;
    const int wid  = t >> 6;
    const int lane = t & 63;
    const float4* src4 = (const float4*)(sim + (size_t)row * HW);

    float vmax = -3.4e38f;
    int   vidx = 0;
    #pragma unroll
    for (int p = 0; p < 16; ++p) {
        int i4 = p * 256 + t;
        float4 v = src4[i4];
        *(float4*)&rowbuf[i4 * 4] = v;
        int base = i4 * 4;
        if (v.x > vmax) { vmax = v.x; vidx = base; }
        if (v.y > vmax) { vmax = v.y; vidx = base + 1; }
        if (v.z > vmax) { vmax = v.z; vidx = base + 2; }
        if (v.w > vmax) { vmax = v.w; vidx = base + 3; }
    }
    #pragma unroll
    for (int off = 32; off > 0; off >>= 1) {
        float ov = __shfl_down(vmax, off);
        int   oi = __shfl_down(vidx, off);
        if (ov > vmax || (ov == vmax && oi < vidx)) { vmax = ov; vidx = oi; }
    }
    if (lane == 0) { s_pm[wid] = vmax; s_pi[wid] = vidx; }
    __syncthreads();
    if (t == 0) {
        float gm = s_pm[0]; int gi = s_pi[0];
        #pragma unroll
        for (int wv = 1; wv < 4; ++wv) {
            float ov = s_pm[wv]; int oi = s_pi[wv];
            if (ov > gm || (ov == gm && oi < gi)) { gm = ov; gi = oi; }
        }
        s_gmax = gm; s_gidx = gi;
    }
    __syncthreads();
    const float gmax = s_gmax;

    float z = 0.f, wx = 0.f, wy = 0.f;
    #pragma unroll
    for (int p = 0; p < 16; ++p) {
        int i4 = p * 256 + t;
        float4 v = *(const float4*)&rowbuf[i4 * 4];
        int i = i4 * 4;
        float e0 = __expf(v.x - gmax), e1 = __expf(v.y - gmax);
        float e2 = __expf(v.z - gmax), e3 = __expf(v.w - gmax);
        z += (e0 + e1) + (e2 + e3);
        float cy = (float)(i >> 7) + 0.5f;
        float cx0 = (float)(i & (Ww - 1)) + 0.5f;
        wx += e0 * cx0 + e1 * (cx0 + 1.f) + e2 * (cx0 + 2.f) + e3 * (cx0 + 3.f);
        wy += (e0 + e1 + e2 + e3) * cy;
    }
    #pragma unroll
    for (int off = 32; off > 0; off >>= 1) {
        z  += __shfl_down(z, off);
        wx += __shfl_down(wx, off);
        wy += __shfl_down(wy, off);
    }
    if (lane == 0) { s_red[wid][0] = z; s_red[wid][1] = wx; s_red[wid][2] = wy; }
    __syncthreads();

    if (t == 0) {
        float Z = 0.f, WX = 0.f, WY = 0.f;
        #pragma unroll
        for (int wv = 0; wv < 4; ++wv) { Z += s_red[wv][0]; WX += s_red[wv][1]; WY += s_red[wv][2]; }

        out[(size_t)row * 2 + 0] = (WX / Z) * (1.0f / (float)Ww);
        out[(size_t)row * 2 + 1] = (WY / Z) * (1.0f / (float)Hh);

        int p  = s_gidx;
        int pr = p / Hh;
        int pc = p % Hh;
        float lsum = 0.f, lwx = 0.f, lwy = 0.f;
        #pragma unroll
        for (int di = -1; di <= 1; ++di) {
            #pragma unroll
            for (int dj = -1; dj <= 1; ++dj) {
                int r = pr + di, c = pc + dj;
                if (r >= 0 && r < Ww && c >= 0 && c < Hh) {
                    int k = r * Hh + c;
                    float e = __expf(rowbuf[k] - gmax);
                    lsum += e;
                    lwx  += e * ((float)(k & (Ww - 1)) + 0.5f);
                    lwy  += e * ((float)(k >> 7) + 0.5f);
                }
            }
        }
        float denom = lsum + 1e-10f * Z;
        out[PROPS_OFF + (size_t)row * 2 + 0] = (lwx / denom) * (1.0f / (float)Ww);
        out[PROPS_OFF + (size_t)row * 2 + 1] = (lwy / denom) * (1.0f / (float)Hh);
    }
}

extern "C" void kernel_launch(void* const* d_in, const int* in_sizes, int n_in,
                              void* d_out, int out_size, void* d_ws, size_t ws_size,
                              hipStream_t stream) {
    const float* Q = (const float*)d_in[0];   // [hw, bs, c]
    const float* S = (const float*)d_in[1];   // [nq, bs, c]
    float* out = (float*)d_out;

    const size_t splitElems = (size_t)BS * NQP * C;            // 458752 halves per array
    const size_t splitBytes = splitElems * 2 * sizeof(_Float16);
    const size_t nPart = (size_t)BS * NQ * NBLK;               // 204800
    const size_t pOff  = (splitBytes + 255) & ~(size_t)255;
    const size_t wsNeeded = pOff + nPart * 4 * sizeof(float);

    if (ws_size >= wsNeeded) {
        _Float16* shi = (_Float16*)d_ws;
        _Float16* slo = shi + splitElems;
        float* pm  = (float*)((char*)d_ws + pOff);
        float* pz  = pm + nPart;
        float* pwx = pz + nPart;
        int*   pidx = (int*)(pwx + nPart);
        split_S_kernel<<<dim3((unsigned)((splitElems / 4 + 255) / 256)), 256, 0, stream>>>(S, shi, slo);
        gemm_kernel<true><<<dim3(HW / BM, BS), 256, 0, stream>>>(Q, S, shi, slo, out,
                                                                 pm, pz, pwx, pidx);
        finalize_kernel<<<dim3(BS * NQ / 4), 256, 0, stream>>>(out + SIM_OFF, pm, pz, pwx, pidx, out);
    } else {
        gemm_kernel<false><<<dim3(HW / BM, BS), 256, 0, stream>>>(Q, S, nullptr, nullptr, out,
                                                                  nullptr, nullptr, nullptr, nullptr);
        reduce_kernel<<<dim3(BS * NQ), 256, 0, stream>>>(out + SIM_OFF, out);
    }
}

// Round 11
// 128.220 us; speedup vs baseline: 1.3812x; 1.3812x over previous
//
#include <hip/hip_runtime.h>
#include <math.h>

// Problem dims (fixed by setup_inputs)
#define HW   16384
#define BS   16
#define C    256
#define NQ   100
#define NQP  112          // padded nq (7 x 16)
#define Hh   128
#define Ww   128

// output layout offsets (floats)
#define SIM_OFF   3200                 // after proposal_for_loss [16,100,2]
#define PROPS_OFF (3200 + 26214400)    // after similarity [16,100,16384]

#define BM 256           // hw per block (2 grid rows) -- 84 MFMA/step, mandatory
#define BK 32            // k per step (== MFMA K)
#define NBLK (HW / BM)   // 64 partials per row

typedef _Float16 half8 __attribute__((ext_vector_type(8)));
typedef float f32x4 __attribute__((ext_vector_type(4)));

__device__ __forceinline__ void gll16(const void* gp, void* lp) {
    __builtin_amdgcn_global_load_lds((const __attribute__((address_space(1))) void*)gp,
                                     (__attribute__((address_space(3))) void*)lp, 16, 0, 0);
}

__device__ __forceinline__ void split8(const float4 a, const float4 b, half8& hi, half8& lo) {
    float f[8] = {a.x, a.y, a.z, a.w, b.x, b.y, b.z, b.w};
    _Float16 h[8], l[8];
    #pragma unroll
    for (int i = 0; i < 8; ++i) {
        h[i] = (_Float16)f[i];
        l[i] = (_Float16)(f[i] - (float)h[i]);
    }
    hi = *(half8*)h;
    lo = *(half8*)l;
}

// ---------------- S pre-split kernel ----------------
// S [nq, bs, c] fp32 -> Shi/Slo [bs][112][256] fp16 (rows >= NQ zero)
__global__ __launch_bounds__(256) void split_S_kernel(const float* __restrict__ S,
                                                      _Float16* __restrict__ shi,
                                                      _Float16* __restrict__ slo)
{
    int idx4 = blockIdx.x * 256 + threadIdx.x;
    int idx = idx4 * 4;
    if (idx >= BS * NQP * C) return;
    int b = idx / (NQP * C);
    int rem = idx - b * (NQP * C);
    int n = rem / C;
    int k = rem - n * C;
    float4 v = make_float4(0.f, 0.f, 0.f, 0.f);
    if (n < NQ) v = *(const float4*)(S + ((size_t)n * BS + b) * C + k);
    _Float16 h[4], l[4];
    float f[4] = {v.x, v.y, v.z, v.w};
    #pragma unroll
    for (int i = 0; i < 4; ++i) {
        h[i] = (_Float16)f[i];
        l[i] = (_Float16)(f[i] - (float)h[i]);
    }
    *(uint2*)(shi + idx) = *(uint2*)h;
    *(uint2*)(slo + idx) = *(uint2*)l;
}

// ---------------- barrier-free split-fp16 MFMA GEMM + fused row stats ----------------
// sim[b][n][k] = sum_c S[n][b][c] * Q[k][b][c]
// A = Q (hw), B = S (nq). Wave stages ONLY its own Q rows (wid*64..+63) ->
// LDS Q tile is wave-private -> NO barriers in the K loop. Q double-buffered
// (WAR-safe). S hi/lo fragments read directly from the L2-resident pre-split
// workspace; stage(next) issued AFTER the S loads so the MFMA's S-wait is a
// counted vmcnt leaving the Q prefetch in flight.
template<bool USE_WS>
__global__ __launch_bounds__(256, 2) void gemm_kernel(const float* __restrict__ Q,
                                                      const float* __restrict__ S,
                                                      const _Float16* __restrict__ ShiG,
                                                      const _Float16* __restrict__ SloG,
                                                      float* __restrict__ out,
                                                      float* __restrict__ pm,
                                                      float* __restrict__ pz,
                                                      float* __restrict__ pwx,
                                                      float* __restrict__ pwy,
                                                      int* __restrict__ pidx)
{
    __shared__ __align__(16) float Qf[2][BM * BK];   // 2 x 32 KB, swizzled chunks
    __shared__ __align__(16) float Ws[NQP][4][4];    // per-(nq,wid) {m, idx, z, wx}

    const int b    = blockIdx.y;
    const int hw0  = blockIdx.x * BM;
    const int t    = threadIdx.x;
    const int wid  = t >> 6;
    const int lane = t & 63;
    const int lr   = lane & 15;    // A-row / B-col within fragment
    const int lg   = lane >> 4;    // k-group (0..3)

    // acc[am][bn]: hw = wid*64 + 16*am + 4*lg + j, nq = 16*bn + lr
    f32x4 acc[4][7];
    #pragma unroll
    for (int am = 0; am < 4; ++am)
        #pragma unroll
        for (int bn = 0; bn < 7; ++bn)
            acc[am][bn] = (f32x4)(0.f);

    // staging: lane l -> row rt+(l>>3), LDS chunk slot (l&7); source chunk
    // pre-swizzled so LDS slot c of row r holds global chunk c ^ (r&7).
    const int q_r8 = lane >> 3;
    const int q_gc = (lane & 7) ^ q_r8;

    auto stageQ = [&](int buf, int k0) {
        #pragma unroll
        for (int p = 0; p < 8; ++p) {
            int rt = wid * 64 + p * 8;             // wave-private rows
            const float* g = Q + ((size_t)(hw0 + rt + q_r8) * BS + b) * C + k0 + q_gc * 4;
            gll16(g, &Qf[buf][rt * BK]);
        }
    };

    stageQ(0, 0);
    for (int step = 0; step < 8; ++step) {
        const int k0  = step * BK;
        const int cur = step & 1;

        // 1. Q fragment ds_reads (wait only on own gll16(cur), aged one step)
        float4 qa[4], qb[4];
        #pragma unroll
        for (int am = 0; am < 4; ++am) {
            int row = wid * 64 + 16 * am + lr;
            int r7 = row & 7;
            qa[am] = *(const float4*)&Qf[cur][row * BK + (((2 * lg + 0) ^ r7) << 2)];
            qb[am] = *(const float4*)&Qf[cur][row * BK + (((2 * lg + 1) ^ r7) << 2)];
        }

        // 2. S fragment loads (L2-resident), BEFORE stage(next): the MFMA's
        //    S-wait becomes a counted vmcnt with the prefetch still in flight
        half8 shi[7], slo[7];
        #pragma unroll
        for (int bn = 0; bn < 7; ++bn) {
            if (USE_WS) {
                size_t off = ((size_t)b * NQP + 16 * bn + lr) * C + k0 + 8 * lg;
                shi[bn] = *(const half8*)(ShiG + off);
                slo[bn] = *(const half8*)(SloG + off);
            } else {
                int row = 16 * bn + lr;
                if (row < NQ) {
                    const float* g = S + ((size_t)row * BS + b) * C + k0 + 8 * lg;
                    float4 sa = *(const float4*)g;
                    float4 sb = *(const float4*)(g + 4);
                    split8(sa, sb, shi[bn], slo[bn]);
                } else {
                    shi[bn] = (half8)(_Float16)0.f;
                    slo[bn] = (half8)(_Float16)0.f;
                }
            }
        }

        // 3. prefetch next K tile (no barrier; wave-private, double-buffered)
        if (step < 7) stageQ(cur ^ 1, k0 + BK);

        // 4. split Q (overlaps S latency)
        half8 qhi[4], qlo[4];
        #pragma unroll
        for (int am = 0; am < 4; ++am) split8(qa[am], qb[am], qhi[am], qlo[am]);

        // 5. 3-pass MFMA
        #pragma unroll
        for (int bn = 0; bn < 7; ++bn)
            #pragma unroll
            for (int am = 0; am < 4; ++am) {
                acc[am][bn] = __builtin_amdgcn_mfma_f32_16x16x32_f16(qhi[am], shi[bn], acc[am][bn], 0, 0, 0);
                acc[am][bn] = __builtin_amdgcn_mfma_f32_16x16x32_f16(qhi[am], slo[bn], acc[am][bn], 0, 0, 0);
                acc[am][bn] = __builtin_amdgcn_mfma_f32_16x16x32_f16(qlo[am], shi[bn], acc[am][bn], 0, 0, 0);
            }
    }

    // ---- epilogue: sim store (dwordx4) + per-row stats (lane-local) ----
    float* simb = out + SIM_OFF;
    const int hwl0 = wid * 64 + 4 * lg;            // local hw base (0..255)
    #pragma unroll
    for (int bn = 0; bn < 7; ++bn) {
        int nq = 16 * bn + lr;
        if (nq < NQ) {
            size_t rbase = ((size_t)(b * NQ + nq)) * HW + hw0 + hwl0;
            #pragma unroll
            for (int am = 0; am < 4; ++am)
                *(float4*)&simb[rbase + 16 * am] =
                    make_float4(acc[am][bn][0], acc[am][bn][1], acc[am][bn][2], acc[am][bn][3]);
        }
        if (USE_WS) {
            // per-thread max/argmax over 16 register values (ascending local idx,
            // strict > -> lowest idx wins ties)
            float vm = acc[0][bn][0];
            int   ci = hwl0;
            #pragma unroll
            for (int am = 0; am < 4; ++am)
                #pragma unroll
                for (int j = 0; j < 4; ++j) {
                    float v = acc[am][bn][j];
                    if (v > vm) { vm = v; ci = hwl0 + 16 * am + j; }
                }
            float z = 0.f, wx = 0.f;
            #pragma unroll
            for (int am = 0; am < 4; ++am)
                #pragma unroll
                for (int j = 0; j < 4; ++j) {
                    float e = __expf(acc[am][bn][j] - vm);
                    z += e;
                    wx += e * ((float)((hwl0 + 16 * am + j) & 127) + 0.5f);
                }
            // 2-step ladder over the 4 lg-lanes holding this nq (xor 16, 32)
            #pragma unroll
            for (int off = 16; off < 64; off <<= 1) {
                float om = __shfl_xor(vm, off);
                int   oc = __shfl_xor(ci, off);
                float oz = __shfl_xor(z, off);
                float ox = __shfl_xor(wx, off);
                bool take = (om > vm) || (om == vm && oc < ci);
                float mn = take ? om : vm;
                float ss = __expf(vm - mn);
                float so = __expf(om - mn);
                z  = z * ss + oz * so;
                wx = wx * ss + ox * so;
                vm = mn;
                ci = take ? oc : ci;
            }
            if (lg == 0) {
                f32x4 tu = {vm, __int_as_float(ci), z, wx};
                *(f32x4*)&Ws[nq][wid][0] = tu;
            }
        }
    }
    if (USE_WS) {
        __syncthreads();
        if (t < NQ) {
            int nq = t;
            float M = -3.4e38f; int gi = 0;
            float mw[4], zw[4], xw[4]; int cw[4];
            #pragma unroll
            for (int w = 0; w < 4; ++w) {
                f32x4 tu = *(const f32x4*)&Ws[nq][w][0];
                mw[w] = tu[0]; cw[w] = __float_as_int(tu[1]); zw[w] = tu[2]; xw[w] = tu[3];
                if (mw[w] > M || (mw[w] == M && cw[w] < gi)) { M = mw[w]; gi = cw[w]; }
            }
            float ybase = (float)(hw0 >> 7) + 0.5f;
            float Zp = 0.f, WXp = 0.f, WYp = 0.f;
            #pragma unroll
            for (int w = 0; w < 4; ++w) {
                float s = __expf(mw[w] - M);
                Zp  += zw[w] * s;
                WXp += xw[w] * s;
                WYp += zw[w] * s * (ybase + (float)(w >> 1));   // y uniform per wid
            }
            size_t pbase = ((size_t)b * NBLK + blockIdx.x) * NQ + nq;
            pm[pbase] = M; pz[pbase] = Zp; pwx[pbase] = WXp; pwy[pbase] = WYp;
            pidx[pbase] = hw0 + gi;
        }
    }
}

// ---------------- finalize: combine 64 partials per row ----------------
__global__ __launch_bounds__(256) void finalize_kernel(const float* __restrict__ sim,
                                                       const float* __restrict__ pm,
                                                       const float* __restrict__ pz,
                                                       const float* __restrict__ pwx,
                                                       const float* __restrict__ pwy,
                                                       const int* __restrict__ pidx,
                                                       float* __restrict__ out)
{
    const int rglob = blockIdx.x * 4 + (threadIdx.x >> 6);  // 0..1599 = b*NQ + n
    const int lane  = threadIdx.x & 63;                     // = partial block id
    const int b     = rglob / NQ;
    const int n     = rglob - b * NQ;
    const size_t base = ((size_t)b * NBLK + lane) * NQ + n;

    float m  = pm[base];
    float z  = pz[base];
    float wx = pwx[base];
    float wy = pwy[base];
    int   gi = pidx[base];

    float v = m; int vi = gi;
    #pragma unroll
    for (int off = 1; off < 64; off <<= 1) {
        float ov = __shfl_xor(v, off);
        int   oi = __shfl_xor(vi, off);
        if (ov > v || (ov == v && oi < vi)) { v = ov; vi = oi; }
    }
    float s  = __expf(m - v);
    float Z  = z * s;
    float WX = wx * s;
    float WY = wy * s;
    #pragma unroll
    for (int off = 1; off < 64; off <<= 1) {
        Z  += __shfl_xor(Z, off);
        WX += __shfl_xor(WX, off);
        WY += __shfl_xor(WY, off);
    }
    if (lane == 0) {
        out[(size_t)rglob * 2 + 0] = (WX / Z) * (1.f / 128.f);
        out[(size_t)rglob * 2 + 1] = (WY / Z) * (1.f / 128.f);
        const float* srow = sim + (size_t)rglob * HW;
        int pr = vi >> 7, pc = vi & 127;
        float ls = 0.f, lx = 0.f, ly = 0.f;
        #pragma unroll
        for (int dr = -1; dr <= 1; ++dr) {
            #pragma unroll
            for (int dc = -1; dc <= 1; ++dc) {
                int r = pr + dr, c = pc + dc;
                if (r >= 0 && r < Ww && c >= 0 && c < Hh) {
                    int k = r * Hh + c;
                    float e = __expf(srow[k] - v);
                    ls += e;
                    lx += e * ((float)(k & 127) + 0.5f);
                    ly += e * ((float)(k >> 7) + 0.5f);
                }
            }
        }
        float denom = ls + 1e-10f * Z;
        out[PROPS_OFF + (size_t)rglob * 2 + 0] = (lx / denom) * (1.f / 128.f);
        out[PROPS_OFF + (size_t)rglob * 2 + 1] = (ly / denom) * (1.f / 128.f);
    }
}

// ---------------- fallback row-reduction kernel (no-ws path) ----------------
__global__ __launch_bounds__(256) void reduce_kernel(const float* __restrict__ sim,
                                                     float* __restrict__ out)
{
    __shared__ float rowbuf[HW];
    __shared__ float s_pm[4];
    __shared__ int   s_pi[4];
    __shared__ float s_red[4][3];
    __shared__ float s_gmax;
    __shared__ int   s_gidx;

    const int row = blockIdx.x;
    const int t   = threadIdx.x;
    const int wid  = t >> 6;
    const int lane = t & 63;
    const float4* src4 = (const float4*)(sim + (size_t)row * HW);

    float vmax = -3.4e38f;
    int   vidx = 0;
    #pragma unroll
    for (int p = 0; p < 16; ++p) {
        int i4 = p * 256 + t;
        float4 v = src4[i4];
        *(float4*)&rowbuf[i4 * 4] = v;
        int base = i4 * 4;
        if (v.x > vmax) { vmax = v.x; vidx = base; }
        if (v.y > vmax) { vmax = v.y; vidx = base + 1; }
        if (v.z > vmax) { vmax = v.z; vidx = base + 2; }
        if (v.w > vmax) { vmax = v.w; vidx = base + 3; }
    }
    #pragma unroll
    for (int off = 32; off > 0; off >>= 1) {
        float ov = __shfl_down(vmax, off);
        int   oi = __shfl_down(vidx, off);
        if (ov > vmax || (ov == vmax && oi < vidx)) { vmax = ov; vidx = oi; }
    }
    if (lane == 0) { s_pm[wid] = vmax; s_pi[wid] = vidx; }
    __syncthreads();
    if (t == 0) {
        float gm = s_pm[0]; int gi = s_pi[0];
        #pragma unroll
        for (int wv = 1; wv < 4; ++wv) {
            float ov = s_pm[wv]; int oi = s_pi[wv];
            if (ov > gm || (ov == gm && oi < gi)) { gm = ov; gi = oi; }
        }
        s_gmax = gm; s_gidx = gi;
    }
    __syncthreads();
    const float gmax = s_gmax;

    float z = 0.f, wx = 0.f, wy = 0.f;
    #pragma unroll
    for (int p = 0; p < 16; ++p) {
        int i4 = p * 256 + t;
        float4 v = *(const float4*)&rowbuf[i4 * 4];
        int i = i4 * 4;
        float e0 = __expf(v.x - gmax), e1 = __expf(v.y - gmax);
        float e2 = __expf(v.z - gmax), e3 = __expf(v.w - gmax);
        z += (e0 + e1) + (e2 + e3);
        float cy = (float)(i >> 7) + 0.5f;
        float cx0 = (float)(i & (Ww - 1)) + 0.5f;
        wx += e0 * cx0 + e1 * (cx0 + 1.f) + e2 * (cx0 + 2.f) + e3 * (cx0 + 3.f);
        wy += (e0 + e1 + e2 + e3) * cy;
    }
    #pragma unroll
    for (int off = 32; off > 0; off >>= 1) {
        z  += __shfl_down(z, off);
        wx += __shfl_down(wx, off);
        wy += __shfl_down(wy, off);
    }
    if (lane == 0) { s_red[wid][0] = z; s_red[wid][1] = wx; s_red[wid][2] = wy; }
    __syncthreads();

    if (t == 0) {
        float Z = 0.f, WX = 0.f, WY = 0.f;
        #pragma unroll
        for (int wv = 0; wv < 4; ++wv) { Z += s_red[wv][0]; WX += s_red[wv][1]; WY += s_red[wv][2]; }

        out[(size_t)row * 2 + 0] = (WX / Z) * (1.0f / (float)Ww);
        out[(size_t)row * 2 + 1] = (WY / Z) * (1.0f / (float)Hh);

        int p  = s_gidx;
        int pr = p / Hh;
        int pc = p % Hh;
        float lsum = 0.f, lwx = 0.f, lwy = 0.f;
        #pragma unroll
        for (int di = -1; di <= 1; ++di) {
            #pragma unroll
            for (int dj = -1; dj <= 1; ++dj) {
                int r = pr + di, c = pc + dj;
                if (r >= 0 && r < Ww && c >= 0 && c < Hh) {
                    int k = r * Hh + c;
                    float e = __expf(rowbuf[k] - gmax);
                    lsum += e;
                    lwx  += e * ((float)(k & (Ww - 1)) + 0.5f);
                    lwy  += e * ((float)(k >> 7) + 0.5f);
                }
            }
        }
        float denom = lsum + 1e-10f * Z;
        out[PROPS_OFF + (size_t)row * 2 + 0] = (lwx / denom) * (1.0f / (float)Ww);
        out[PROPS_OFF + (size_t)row * 2 + 1] = (lwy / denom) * (1.0f / (float)Hh);
    }
}

extern "C" void kernel_launch(void* const* d_in, const int* in_sizes, int n_in,
                              void* d_out, int out_size, void* d_ws, size_t ws_size,
                              hipStream_t stream) {
    const float* Q = (const float*)d_in[0];   // [hw, bs, c]
    const float* S = (const float*)d_in[1];   // [nq, bs, c]
    float* out = (float*)d_out;

    const size_t splitElems = (size_t)BS * NQP * C;            // 458752 halves per array
    const size_t splitBytes = splitElems * 2 * sizeof(_Float16);
    const size_t nPart = (size_t)BS * NQ * NBLK;               // 102400
    const size_t pOff  = (splitBytes + 255) & ~(size_t)255;
    const size_t wsNeeded = pOff + nPart * 5 * sizeof(float);

    if (ws_size >= wsNeeded) {
        _Float16* shi = (_Float16*)d_ws;
        _Float16* slo = shi + splitElems;
        float* pm  = (float*)((char*)d_ws + pOff);
        float* pz  = pm + nPart;
        float* pwx = pz + nPart;
        float* pwy = pwx + nPart;
        int*   pidx = (int*)(pwy + nPart);
        split_S_kernel<<<dim3((unsigned)((splitElems / 4 + 255) / 256)), 256, 0, stream>>>(S, shi, slo);
        gemm_kernel<true><<<dim3(HW / BM, BS), 256, 0, stream>>>(Q, S, shi, slo, out,
                                                                 pm, pz, pwx, pwy, pidx);
        finalize_kernel<<<dim3(BS * NQ / 4), 256, 0, stream>>>(out + SIM_OFF, pm, pz, pwx, pwy, pidx, out);
    } else {
        gemm_kernel<false><<<dim3(HW / BM, BS), 256, 0, stream>>>(Q, S, nullptr, nullptr, out,
                                                                  nullptr, nullptr, nullptr, nullptr, nullptr);
        reduce_kernel<<<dim3(BS * NQ), 256, 0, stream>>>(out + SIM_OFF, out);
    }
}

// Round 12
// 108.866 us; speedup vs baseline: 1.6267x; 1.1778x over previous
//
#include <hip/hip_runtime.h>
#include <math.h>

// Problem dims (fixed by setup_inputs)
#define HW   16384
#define BS   16
#define C    256
#define NQ   100
#define NQP  112          // padded nq (7 x 16)
#define Hh   128
#define Ww   128

// output layout offsets (floats)
#define SIM_OFF   3200                 // after proposal_for_loss [16,100,2]
#define PROPS_OFF (3200 + 26214400)    // after similarity [16,100,16384]

#define BM 256           // hw per block (2 grid rows) -- 84->28 MFMA/step
#define BK 32            // k per step (== MFMA K)
#define NBLK (HW / BM)   // 64 partials per row

typedef _Float16 half8 __attribute__((ext_vector_type(8)));
typedef float f32x4 __attribute__((ext_vector_type(4)));

__device__ __forceinline__ void gll16(const void* gp, void* lp) {
    __builtin_amdgcn_global_load_lds((const __attribute__((address_space(1))) void*)gp,
                                     (__attribute__((address_space(3))) void*)lp, 16, 0, 0);
}

__device__ __forceinline__ half8 cvt8(const float4 a, const float4 b) {
    _Float16 h[8] = {(_Float16)a.x, (_Float16)a.y, (_Float16)a.z, (_Float16)a.w,
                     (_Float16)b.x, (_Float16)b.y, (_Float16)b.z, (_Float16)b.w};
    return *(half8*)h;
}

// ---------------- S pre-convert kernel ----------------
// S [nq, bs, c] fp32 -> Sh [bs][112][256] fp16 (rows >= NQ zero)
__global__ __launch_bounds__(256) void conv_S_kernel(const float* __restrict__ S,
                                                     _Float16* __restrict__ sh)
{
    int idx4 = blockIdx.x * 256 + threadIdx.x;
    int idx = idx4 * 4;
    if (idx >= BS * NQP * C) return;
    int b = idx / (NQP * C);
    int rem = idx - b * (NQP * C);
    int n = rem / C;
    int k = rem - n * C;
    float4 v = make_float4(0.f, 0.f, 0.f, 0.f);
    if (n < NQ) v = *(const float4*)(S + ((size_t)n * BS + b) * C + k);
    _Float16 h[4] = {(_Float16)v.x, (_Float16)v.y, (_Float16)v.z, (_Float16)v.w};
    *(uint2*)(sh + idx) = *(uint2*)h;
}

// ---------------- single-pass fp16 MFMA GEMM + fused row stats ----------------
// sim[b][n][k] = sum_c S[n][b][c] * Q[k][b][c]
// A = Q (hw), B = S (nq): D col (lane&15) = nq -> row stats lane-local.
// Q fp32 and S fp16 staged via global_load_lds (source-swizzled chunks),
// single LDS buffer, one stage + 2 barriers per K-step (R9 skeleton).
template<bool USE_WS>
__global__ __launch_bounds__(256, 2) void gemm_kernel(const float* __restrict__ Q,
                                                      const float* __restrict__ S,
                                                      const _Float16* __restrict__ ShG,
                                                      float* __restrict__ out,
                                                      float* __restrict__ pm,
                                                      float* __restrict__ pz,
                                                      float* __restrict__ pwx,
                                                      float* __restrict__ pwy,
                                                      int* __restrict__ pidx)
{
    // Qf: 256 rows x 32 f32 (128 B row). chunk c (16B) stored at slot c ^ (row&7).
    __shared__ __align__(16) float    Qf[BM * BK];         // 32 KB
    // SH: 112 rows x 32 f16 (64 B row). chunk c (16B) at slot c ^ ((row>>1)&3).
    __shared__ __align__(16) _Float16 SH[NQP * BK];        // 7 KB
    __shared__ __align__(16) float Ws[NQP][4][4];          // per-(nq,wid) {m,idx,z,wx}

    const int b    = blockIdx.y;
    const int hw0  = blockIdx.x * BM;
    const int t    = threadIdx.x;
    const int wid  = t >> 6;
    const int lane = t & 63;
    const int lr   = lane & 15;    // A-row / B-col within fragment
    const int lg   = lane >> 4;    // k-group (0..3)

    // acc[am][bn]: hw = wid*64 + 16*am + 4*lg + j, nq = 16*bn + lr
    f32x4 acc[4][7];
    #pragma unroll
    for (int am = 0; am < 4; ++am)
        #pragma unroll
        for (int bn = 0; bn < 7; ++bn)
            acc[am][bn] = (f32x4)(0.f);

    // staging lane decomposition
    const int q_r8 = lane >> 3;                       // row within 8-row group
    const int q_gc = (lane & 7) ^ q_r8;               // pre-swizzled global chunk (f32 x4)
    const int s_r  = lane >> 2;                       // row within 16-row group
    const int s_gc = (lane & 3) ^ ((lane >> 3) & 3);  // pre-swizzled global chunk (f16 x8)

    for (int k0 = 0; k0 < C; k0 += BK) {
        // ---- stage Q tile via global_load_lds (8 insts/thread, 8 rows each) ----
        #pragma unroll
        for (int p = 0; p < 8; ++p) {
            int rt = wid * 64 + p * 8;
            const float* g = Q + ((size_t)(hw0 + rt + q_r8) * BS + b) * C + k0 + q_gc * 4;
            gll16(g, &Qf[rt * BK]);
        }
        // ---- stage S fp16 tile (7 gll16 spread over waves) ----
        if (USE_WS) {
            for (int i = wid; i < 7; i += 4) {
                int r0 = i * 16;
                const _Float16* g = ShG + ((size_t)b * NQP + r0 + s_r) * C + k0 + s_gc * 8;
                gll16(g, &SH[r0 * BK]);
            }
        }
        __syncthreads();

        // ---- A fragments (Q): read swizzled f32 chunks, convert to fp16 ----
        half8 qh[4];
        #pragma unroll
        for (int am = 0; am < 4; ++am) {
            int row = wid * 64 + 16 * am + lr;
            int r7 = row & 7;
            float4 qa = *(const float4*)&Qf[row * BK + (((2 * lg + 0) ^ r7) << 2)];
            float4 qb = *(const float4*)&Qf[row * BK + (((2 * lg + 1) ^ r7) << 2)];
            qh[am] = cvt8(qa, qb);
        }

        // ---- B fragments (S) + single-pass MFMA ----
        #pragma unroll
        for (int bn = 0; bn < 7; ++bn) {
            int row = 16 * bn + lr;
            half8 sh;
            if (USE_WS) {
                int slot = lg ^ ((row >> 1) & 3);
                sh = *(const half8*)&SH[row * BK + slot * 8];
            } else {
                if (row < NQ) {
                    const float* g = S + ((size_t)row * BS + b) * C + k0 + 8 * lg;
                    float4 sa = *(const float4*)g;
                    float4 sb = *(const float4*)(g + 4);
                    sh = cvt8(sa, sb);
                } else {
                    sh = (half8)(_Float16)0.f;
                }
            }
            #pragma unroll
            for (int am = 0; am < 4; ++am)
                acc[am][bn] = __builtin_amdgcn_mfma_f32_16x16x32_f16(qh[am], sh, acc[am][bn], 0, 0, 0);
        }
        __syncthreads();
    }

    // ---- epilogue: sim store (dwordx4) + per-row stats (lane-local) ----
    float* simb = out + SIM_OFF;
    const int hwl0 = wid * 64 + 4 * lg;            // local hw base (0..255)
    #pragma unroll
    for (int bn = 0; bn < 7; ++bn) {
        int nq = 16 * bn + lr;
        if (nq < NQ) {
            size_t rbase = ((size_t)(b * NQ + nq)) * HW + hw0 + hwl0;
            #pragma unroll
            for (int am = 0; am < 4; ++am)
                *(float4*)&simb[rbase + 16 * am] =
                    make_float4(acc[am][bn][0], acc[am][bn][1], acc[am][bn][2], acc[am][bn][3]);
        }
        if (USE_WS) {
            // per-thread max/argmax over 16 register values (ascending local idx,
            // strict > -> lowest idx wins ties)
            float vm = acc[0][bn][0];
            int   ci = hwl0;
            #pragma unroll
            for (int am = 0; am < 4; ++am)
                #pragma unroll
                for (int j = 0; j < 4; ++j) {
                    float v = acc[am][bn][j];
                    if (v > vm) { vm = v; ci = hwl0 + 16 * am + j; }
                }
            float z = 0.f, wx = 0.f;
            #pragma unroll
            for (int am = 0; am < 4; ++am)
                #pragma unroll
                for (int j = 0; j < 4; ++j) {
                    float e = __expf(acc[am][bn][j] - vm);
                    z += e;
                    wx += e * ((float)((hwl0 + 16 * am + j) & 127) + 0.5f);
                }
            // 2-step ladder over the 4 lg-lanes holding this nq (xor 16, 32)
            #pragma unroll
            for (int off = 16; off < 64; off <<= 1) {
                float om = __shfl_xor(vm, off);
                int   oc = __shfl_xor(ci, off);
                float oz = __shfl_xor(z, off);
                float ox = __shfl_xor(wx, off);
                bool take = (om > vm) || (om == vm && oc < ci);
                float mn = take ? om : vm;
                float ss = __expf(vm - mn);
                float so = __expf(om - mn);
                z  = z * ss + oz * so;
                wx = wx * ss + ox * so;
                vm = mn;
                ci = take ? oc : ci;
            }
            if (lg == 0) {
                f32x4 tu = {vm, __int_as_float(ci), z, wx};
                *(f32x4*)&Ws[nq][wid][0] = tu;
            }
        }
    }
    if (USE_WS) {
        __syncthreads();
        if (t < NQ) {
            int nq = t;
            float M = -3.4e38f; int gi = 0;
            float mw[4], zw[4], xw[4]; int cw[4];
            #pragma unroll
            for (int w = 0; w < 4; ++w) {
                f32x4 tu = *(const f32x4*)&Ws[nq][w][0];
                mw[w] = tu[0]; cw[w] = __float_as_int(tu[1]); zw[w] = tu[2]; xw[w] = tu[3];
                if (mw[w] > M || (mw[w] == M && cw[w] < gi)) { M = mw[w]; gi = cw[w]; }
            }
            float ybase = (float)(hw0 >> 7) + 0.5f;
            float Zp = 0.f, WXp = 0.f, WYp = 0.f;
            #pragma unroll
            for (int w = 0; w < 4; ++w) {
                float s = __expf(mw[w] - M);
                Zp  += zw[w] * s;
                WXp += xw[w] * s;
                WYp += zw[w] * s * (ybase + (float)(w >> 1));   // y uniform per wid
            }
            size_t pbase = ((size_t)b * NBLK + blockIdx.x) * NQ + nq;
            pm[pbase] = M; pz[pbase] = Zp; pwx[pbase] = WXp; pwy[pbase] = WYp;
            pidx[pbase] = hw0 + gi;
        }
    }
}

// ---------------- finalize: combine 64 partials per row ----------------
__global__ __launch_bounds__(256) void finalize_kernel(const float* __restrict__ sim,
                                                       const float* __restrict__ pm,
                                                       const float* __restrict__ pz,
                                                       const float* __restrict__ pwx,
                                                       const float* __restrict__ pwy,
                                                       const int* __restrict__ pidx,
                                                       float* __restrict__ out)
{
    const int rglob = blockIdx.x * 4 + (threadIdx.x >> 6);  // 0..1599 = b*NQ + n
    const int lane  = threadIdx.x & 63;                     // = partial block id
    const int b     = rglob / NQ;
    const int n     = rglob - b * NQ;
    const size_t base = ((size_t)b * NBLK + lane) * NQ + n;

    float m  = pm[base];
    float z  = pz[base];
    float wx = pwx[base];
    float wy = pwy[base];
    int   gi = pidx[base];

    float v = m; int vi = gi;
    #pragma unroll
    for (int off = 1; off < 64; off <<= 1) {
        float ov = __shfl_xor(v, off);
        int   oi = __shfl_xor(vi, off);
        if (ov > v || (ov == v && oi < vi)) { v = ov; vi = oi; }
    }
    float s  = __expf(m - v);
    float Z  = z * s;
    float WX = wx * s;
    float WY = wy * s;
    #pragma unroll
    for (int off = 1; off < 64; off <<= 1) {
        Z  += __shfl_xor(Z, off);
        WX += __shfl_xor(WX, off);
        WY += __shfl_xor(WY, off);
    }
    if (lane == 0) {
        out[(size_t)rglob * 2 + 0] = (WX / Z) * (1.f / 128.f);
        out[(size_t)rglob * 2 + 1] = (WY / Z) * (1.f / 128.f);
        const float* srow = sim + (size_t)rglob * HW;
        int pr = vi >> 7, pc = vi & 127;
        float ls = 0.f, lx = 0.f, ly = 0.f;
        #pragma unroll
        for (int dr = -1; dr <= 1; ++dr) {
            #pragma unroll
            for (int dc = -1; dc <= 1; ++dc) {
                int r = pr + dr, c = pc + dc;
                if (r >= 0 && r < Ww && c >= 0 && c < Hh) {
                    int k = r * Hh + c;
                    float e = __expf(srow[k] - v);
                    ls += e;
                    lx += e * ((float)(k & 127) + 0.5f);
                    ly += e * ((float)(k >> 7) + 0.5f);
                }
            }
        }
        float denom = ls + 1e-10f * Z;
        out[PROPS_OFF + (size_t)rglob * 2 + 0] = (lx / denom) * (1.f / 128.f);
        out[PROPS_OFF + (size_t)rglob * 2 + 1] = (ly / denom) * (1.f / 128.f);
    }
}

// ---------------- fallback row-reduction kernel (no-ws path) ----------------
__global__ __launch_bounds__(256) void reduce_kernel(const float* __restrict__ sim,
                                                     float* __restrict__ out)
{
    __shared__ float rowbuf[HW];
    __shared__ float s_pm[4];
    __shared__ int   s_pi[4];
    __shared__ float s_red[4][3];
    __shared__ float s_gmax;
    __shared__ int   s_gidx;

    const int row = blockIdx.x;
    const int t   = threadIdx.x;
    const int wid  = t >> 6;
    const int lane = t & 63;
    const float4* src4 = (const float4*)(sim + (size_t)row * HW);

    float vmax = -3.4e38f;
    int   vidx = 0;
    #pragma unroll
    for (int p = 0; p < 16; ++p) {
        int i4 = p * 256 + t;
        float4 v = src4[i4];
        *(float4*)&rowbuf[i4 * 4] = v;
        int base = i4 * 4;
        if (v.x > vmax) { vmax = v.x; vidx = base; }
        if (v.y > vmax) { vmax = v.y; vidx = base + 1; }
        if (v.z > vmax) { vmax = v.z; vidx = base + 2; }
        if (v.w > vmax) { vmax = v.w; vidx = base + 3; }
    }
    #pragma unroll
    for (int off = 32; off > 0; off >>= 1) {
        float ov = __shfl_down(vmax, off);
        int   oi = __shfl_down(vidx, off);
        if (ov > vmax || (ov == vmax && oi < vidx)) { vmax = ov; vidx = oi; }
    }
    if (lane == 0) { s_pm[wid] = vmax; s_pi[wid] = vidx; }
    __syncthreads();
    if (t == 0) {
        float gm = s_pm[0]; int gi = s_pi[0];
        #pragma unroll
        for (int wv = 1; wv < 4; ++wv) {
            float ov = s_pm[wv]; int oi = s_pi[wv];
            if (ov > gm || (ov == gm && oi < gi)) { gm = ov; gi = oi; }
        }
        s_gmax = gm; s_gidx = gi;
    }
    __syncthreads();
    const float gmax = s_gmax;

    float z = 0.f, wx = 0.f, wy = 0.f;
    #pragma unroll
    for (int p = 0; p < 16; ++p) {
        int i4 = p * 256 + t;
        float4 v = *(const float4*)&rowbuf[i4 * 4];
        int i = i4 * 4;
        float e0 = __expf(v.x - gmax), e1 = __expf(v.y - gmax);
        float e2 = __expf(v.z - gmax), e3 = __expf(v.w - gmax);
        z += (e0 + e1) + (e2 + e3);
        float cy = (float)(i >> 7) + 0.5f;
        float cx0 = (float)(i & (Ww - 1)) + 0.5f;
        wx += e0 * cx0 + e1 * (cx0 + 1.f) + e2 * (cx0 + 2.f) + e3 * (cx0 + 3.f);
        wy += (e0 + e1 + e2 + e3) * cy;
    }
    #pragma unroll
    for (int off = 32; off > 0; off >>= 1) {
        z  += __shfl_down(z, off);
        wx += __shfl_down(wx, off);
        wy += __shfl_down(wy, off);
    }
    if (lane == 0) { s_red[wid][0] = z; s_red[wid][1] = wx; s_red[wid][2] = wy; }
    __syncthreads();

    if (t == 0) {
        float Z = 0.f, WX = 0.f, WY = 0.f;
        #pragma unroll
        for (int wv = 0; wv < 4; ++wv) { Z += s_red[wv][0]; WX += s_red[wv][1]; WY += s_red[wv][2]; }

        out[(size_t)row * 2 + 0] = (WX / Z) * (1.0f / (float)Ww);
        out[(size_t)row * 2 + 1] = (WY / Z) * (1.0f / (float)Hh);

        int p  = s_gidx;
        int pr = p / Hh;
        int pc = p % Hh;
        float lsum = 0.f, lwx = 0.f, lwy = 0.f;
        #pragma unroll
        for (int di = -1; di <= 1; ++di) {
            #pragma unroll
            for (int dj = -1; dj <= 1; ++dj) {
                int r = pr + di, c = pc + dj;
                if (r >= 0 && r < Ww && c >= 0 && c < Hh) {
                    int k = r * Hh + c;
                    float e = __expf(rowbuf[k] - gmax);
                    lsum += e;
                    lwx  += e * ((float)(k & (Ww - 1)) + 0.5f);
                    lwy  += e * ((float)(k >> 7) + 0.5f);
                }
            }
        }
        float denom = lsum + 1e-10f * Z;
        out[PROPS_OFF + (size_t)row * 2 + 0] = (lwx / denom) * (1.0f / (float)Ww);
        out[PROPS_OFF + (size_t)row * 2 + 1] = (lwy / denom) * (1.0f / (float)Hh);
    }
}

extern "C" void kernel_launch(void* const* d_in, const int* in_sizes, int n_in,
                              void* d_out, int out_size, void* d_ws, size_t ws_size,
                              hipStream_t stream) {
    const float* Q = (const float*)d_in[0];   // [hw, bs, c]
    const float* S = (const float*)d_in[1];   // [nq, bs, c]
    float* out = (float*)d_out;

    const size_t splitElems = (size_t)BS * NQP * C;            // 458752 halves
    const size_t splitBytes = splitElems * sizeof(_Float16);
    const size_t nPart = (size_t)BS * NQ * NBLK;               // 102400
    const size_t pOff  = (splitBytes + 255) & ~(size_t)255;
    const size_t wsNeeded = pOff + nPart * 5 * sizeof(float);

    if (ws_size >= wsNeeded) {
        _Float16* sh = (_Float16*)d_ws;
        float* pm  = (float*)((char*)d_ws + pOff);
        float* pz  = pm + nPart;
        float* pwx = pz + nPart;
        float* pwy = pwx + nPart;
        int*   pidx = (int*)(pwy + nPart);
        conv_S_kernel<<<dim3((unsigned)((splitElems / 4 + 255) / 256)), 256, 0, stream>>>(S, sh);
        gemm_kernel<true><<<dim3(HW / BM, BS), 256, 0, stream>>>(Q, S, sh, out,
                                                                 pm, pz, pwx, pwy, pidx);
        finalize_kernel<<<dim3(BS * NQ / 4), 256, 0, stream>>>(out + SIM_OFF, pm, pz, pwx, pwy, pidx, out);
    } else {
        gemm_kernel<false><<<dim3(HW / BM, BS), 256, 0, stream>>>(Q, S, nullptr, out,
                                                                  nullptr, nullptr, nullptr, nullptr, nullptr);
        reduce_kernel<<<dim3(BS * NQ), 256, 0, stream>>>(out + SIM_OFF, out);
    }
}